// Round 7
// baseline (5021.837 us; speedup 1.0000x reference)
//
#include <hip/hip_runtime.h>
#include <hip/hip_bf16.h>
#include <hip/hip_fp16.h>

typedef unsigned int uint32;
typedef _Float16 hf2 __attribute__((ext_vector_type(2)));

#define NT 1024

// ---------- helpers ----------
__device__ __forceinline__ float bfu(unsigned short v) { return __uint_as_float(((uint32)v) << 16); }
__device__ __forceinline__ unsigned short f2bf(float f) {
    uint32 u = __float_as_uint(f);
    u = (u + 0x7fffu + ((u >> 16) & 1u)) >> 16;
    return (unsigned short)u;
}
__device__ __forceinline__ uint32 pack_f16(float a, float b) {
    __half ha = __float2half_rn(a), hb = __float2half_rn(b);
    return (uint32)__half_as_ushort(ha) | ((uint32)__half_as_ushort(hb) << 16);
}
__device__ __forceinline__ float fast_tanh(float x) {
    x = fminf(fmaxf(x, -15.f), 15.f);
    float e = __expf(2.f * x);
    return __fdividef(e - 1.f, e + 1.f);
}
__device__ __forceinline__ float fast_sigmoid(float x) {
    return __fdividef(1.f, 1.f + __expf(-x));
}
__device__ __forceinline__ float fdot2(uint32 w, uint32 v, float acc) {
#if __has_builtin(__builtin_amdgcn_fdot2)
    return __builtin_amdgcn_fdot2(__builtin_bit_cast(hf2, w), __builtin_bit_cast(hf2, v), acc, false);
#else
    __half2 wh = __builtin_bit_cast(__half2, w), vh = __builtin_bit_cast(__half2, v);
    float2 wf = __half22float2(wh), vf = __half22float2(vh);
    return fmaf(wf.y, vf.y, fmaf(wf.x, vf.x, acc));
#endif
}

// ---------- prep 1: f16 weight packs, 4 regions (uint4-interleaved) ----------
// Gate GEMV K-order: v = [xw(128) | h(256)], pair np covers elems (2np, 2np+1).
// A (regs)  WrA : words [0, 65536): (q*1024+gg)*4+p, q 0..15 -> np=4q+p -> W_ih cols (2np, 2np+1)
// B (LDS)   WlB : words [0, 28672): np*1024+gg,      np 0..27 -> h-pair np -> W_hh cols (2np, 2np+1)
// C (stream)WsC : words [0,102400): (q*1024+gg)*4+p, q 0..24 -> h-pair hp=28+4q+p -> W_hh cols (2hp, 2hp+1)
// D (attn)  WeT : words [0, 32768): (q*1024+ch*128+s)*4+p, q 0..7 -> j0=ch*64+8q+2p -> We[s] cols (j0, j0+1)
__global__ void prep_weights(const float* __restrict__ We, const float* __restrict__ W_ih,
                             const float* __restrict__ W_hh, uint32* __restrict__ WrA,
                             uint32* __restrict__ WlB, uint32* __restrict__ WsC,
                             uint32* __restrict__ WeT) {
    int idx = blockIdx.x * 256 + threadIdx.x;
    if (idx < 65536) {
        int p = idx & 3, gg = (idx >> 2) & 1023, q = idx >> 12;
        int np = 4 * q + p;
        WrA[idx] = pack_f16(W_ih[gg * 128 + 2 * np], W_ih[gg * 128 + 2 * np + 1]);
    } else if (idx < 94208) {
        int i2 = idx - 65536;
        int gg = i2 & 1023, np = i2 >> 10;
        WlB[i2] = pack_f16(W_hh[gg * 256 + 2 * np], W_hh[gg * 256 + 2 * np + 1]);
    } else if (idx < 196608) {
        int i2 = idx - 94208;
        int p = i2 & 3, gg = (i2 >> 2) & 1023, q = i2 >> 12;
        int hp = 28 + 4 * q + p;
        WsC[i2] = pack_f16(W_hh[gg * 256 + 2 * hp], W_hh[gg * 256 + 2 * hp + 1]);
    } else if (idx < 229376) {
        int i2 = idx - 196608;
        int p = i2 & 3, s = (i2 >> 2) & 127, ch = (i2 >> 9) & 7, q = i2 >> 12;
        int j0 = ch * 64 + 8 * q + 2 * p;
        WeT[i2] = pack_f16(We[s * 512 + j0], We[s * 512 + j0 + 1]);
    }
}

// ---------- prep 2: Ux[b,s,n] = sum_t x[b,t,n] * Ue[s,t]  (bf16 out) ----------
__global__ void ux_kernel(const float* __restrict__ x, const float* __restrict__ Ue,
                          unsigned short* __restrict__ Uxg) {
    int b = blockIdx.x >> 1, h = blockIdx.x & 1;
    int n = threadIdx.x & 127, sg = threadIdx.x >> 7;
    int s0 = h * 64 + sg * 16;
    float acc[16];
#pragma unroll
    for (int k = 0; k < 16; ++k) acc[k] = 0.f;
    for (int t0 = 0; t0 < 128; t0 += 16) {
        float xv[16];
#pragma unroll
        for (int tt = 0; tt < 16; ++tt) xv[tt] = x[(b * 128 + t0 + tt) * 128 + n];
#pragma unroll
        for (int k = 0; k < 16; ++k) {
            const float4* uep = (const float4*)(Ue + (s0 + k) * 128 + t0);
            float4 u0 = uep[0], u1 = uep[1], u2 = uep[2], u3 = uep[3];
            acc[k] += xv[0] * u0.x + xv[1] * u0.y + xv[2] * u0.z + xv[3] * u0.w
                    + xv[4] * u1.x + xv[5] * u1.y + xv[6] * u1.z + xv[7] * u1.w
                    + xv[8] * u2.x + xv[9] * u2.y + xv[10] * u2.z + xv[11] * u2.w
                    + xv[12] * u3.x + xv[13] * u3.y + xv[14] * u3.z + xv[15] * u3.w;
        }
    }
#pragma unroll
    for (int k = 0; k < 16; ++k)
        Uxg[b * 16384 + (s0 + k) * 128 + n] = f2bf(acc[k]);
}

// ---------- main: 128 blocks x 1024 thr, one gate per thread. Residency:
// 64 xw-pairs in regs (launch_bounds(1024,4) -> 128-VGPR budget), 28 h-pairs
// in LDS, 100 h-pairs + We streamed with depth-5 dwordx4 prefetch rotation.
// All sync intra-block. ----------
__global__ __launch_bounds__(NT, 4)
void encoder_kernel(const float* __restrict__ x, const float* __restrict__ v_e,
                    const float* __restrict__ b_ih, const float* __restrict__ b_hh,
                    const unsigned short* __restrict__ Uxg, const uint4* __restrict__ WrA4,
                    const uint32* __restrict__ WlB, const uint4* __restrict__ WsC4,
                    const uint4* __restrict__ WeT4, float* __restrict__ out) {
    __shared__ __align__(16) unsigned short Ux_s[16384];  // 32 KB [s][n] bf16
    __shared__ uint32 W_l[29696];   // 116 KB: gate g's 28 pairs at [g*29 .. g*29+27]
    __shared__ uint32 vh_s[192];    // v pairs: [xw(0..64) | h(64..192)]
    __shared__ uint32 hsh_s[256];   // hs pairs: [h(0..128) | c(128..256)]
    __shared__ float scr[1024];     // scratch: part1 / part2 / gates (disjoint lifetimes)
    __shared__ float web_s[128];
    __shared__ float ve_s[128];

    const int tid = threadIdx.x;
    const int b = blockIdx.x;
    const int lane7 = tid & 127;    // s (ph1) / n (ph2)
    const int ch = tid >> 7;        // 8-way chunk (wave-uniform)

    {   // stage Ux tile (coalesced)
        const uint4* src = (const uint4*)(Uxg + b * 16384);
        uint4* dst = (uint4*)Ux_s;
        dst[tid] = src[tid];
        dst[tid + 1024] = src[tid + 1024];
    }
    // stage LDS-resident gate weights: row g = tid, stride 29 (2-way max aliasing)
#pragma unroll
    for (int q = 0; q < 28; ++q) W_l[tid * 29 + q] = WlB[q * 1024 + tid];
    // reg-resident gate weights (all 64 xw pairs as 16 uint4)
    uint4 w_r4[16];
#pragma unroll
    for (int q = 0; q < 16; ++q) w_r4[q] = WrA4[q * 1024 + tid];
    const float bias_r = b_ih[tid] + b_hh[tid];
    float c_r = 0.f;  // c-state (threads 0..255)
    if (tid < 128) ve_s[tid] = v_e[tid];
    if (tid < 192) vh_s[tid] = 0u;
    if (tid < 256) hsh_s[tid] = 0u;
    __syncthreads();

    for (int t = 0; t < 128; ++t) {
        // x_t prefetch for softmax (wave 0)
        float2 xv = make_float2(0.f, 0.f);
        if (tid < 64) xv = *(const float2*)(x + (b * 128 + t) * 128 + 2 * tid);

        // ---- gate GEMV, h-part: LDS-resident 28 pairs ----
        float acc = bias_r;
#pragma unroll
        for (int q = 0; q < 28; ++q) acc = fdot2(W_l[tid * 29 + q], vh_s[64 + q], acc);

        // ---- gate GEMV, h-part: streamed 25 dwordx4 (depth-5 rotation) ----
        {
            uint4 sb[5];
#pragma unroll
            for (int q = 0; q < 5; ++q) sb[q] = WsC4[q * 1024 + tid];
#pragma unroll
            for (int q = 0; q < 25; ++q) {
                uint4 w = sb[q % 5];
                if (q + 5 < 25) sb[q % 5] = WsC4[(q + 5) * 1024 + tid];
                acc = fdot2(w.x, vh_s[92 + 4 * q], acc);
                acc = fdot2(w.y, vh_s[93 + 4 * q], acc);
                acc = fdot2(w.z, vh_s[94 + 4 * q], acc);
                acc = fdot2(w.w, vh_s[95 + 4 * q], acc);
            }
        }

        // ---- ph1: web[s] partials, thread (s=lane7, ch): j-pairs [32ch, 32ch+32) ----
        {
            uint4 wb[8];
#pragma unroll
            for (int q = 0; q < 8; ++q) wb[q] = WeT4[q * 1024 + tid];
            float a1 = 0.f;
#pragma unroll
            for (int q = 0; q < 8; ++q) {
                a1 = fdot2(wb[q].x, hsh_s[ch * 32 + 4 * q + 0], a1);
                a1 = fdot2(wb[q].y, hsh_s[ch * 32 + 4 * q + 1], a1);
                a1 = fdot2(wb[q].z, hsh_s[ch * 32 + 4 * q + 2], a1);
                a1 = fdot2(wb[q].w, hsh_s[ch * 32 + 4 * q + 3], a1);
            }
            scr[tid] = a1;  // [ch][s]
        }
        __syncthreads();  // B1
        if (tid < 128) {
            float w = 0.f;
#pragma unroll
            for (int g = 0; g < 8; ++g) w += scr[g * 128 + tid];
            web_s[tid] = w;
        }
        __syncthreads();  // B2

        // ---- ph2: score partials, thread (n=lane7, ch): s in [16ch, 16ch+16) ----
        {
            float a2 = 0.f;
#pragma unroll 4
            for (int k = 0; k < 16; ++k) {
                int ss = ch * 16 + k;
                a2 += ve_s[ss] * fast_tanh(web_s[ss] + bfu(Ux_s[ss * 128 + lane7]));
            }
            scr[tid] = a2;  // [ch][n]
        }
        __syncthreads();  // B3

        // ---- ph3: softmax + xw publish (wave 0; lane owns n=2l, 2l+1) ----
        if (tid < 64) {
            float v0 = 0.f, v1 = 0.f;
#pragma unroll
            for (int g = 0; g < 8; ++g) {
                v0 += scr[g * 128 + 2 * tid];
                v1 += scr[g * 128 + 2 * tid + 1];
            }
            float m = fmaxf(v0, v1);
#pragma unroll
            for (int off = 32; off > 0; off >>= 1) m = fmaxf(m, __shfl_xor(m, off));
            float e0 = __expf(v0 - m), e1 = __expf(v1 - m);
            float ssum = e0 + e1;
#pragma unroll
            for (int off = 32; off > 0; off >>= 1) ssum += __shfl_xor(ssum, off);
            float inv = __fdividef(1.f, ssum);
            vh_s[tid] = pack_f16(xv.x * e0 * inv, xv.y * e1 * inv);
        }
        __syncthreads();  // B4

        // ---- gate GEMV, xw-part from registers; write gates ----
#pragma unroll
        for (int q = 0; q < 16; ++q) {
            acc = fdot2(w_r4[q].x, vh_s[4 * q + 0], acc);
            acc = fdot2(w_r4[q].y, vh_s[4 * q + 1], acc);
            acc = fdot2(w_r4[q].z, vh_s[4 * q + 2], acc);
            acc = fdot2(w_r4[q].w, vh_s[4 * q + 3], acc);
        }
        scr[tid] = acc;   // gates, [gg]
        __syncthreads();  // B5

        // ---- pointwise + publish h/c (threads 0..255, thread = h-unit j) ----
        if (tid < 256) {
            const int j = tid;
            float gi = scr[j], gf = scr[256 + j], gG = scr[512 + j], go = scr[768 + j];
            float c2 = fast_sigmoid(gf) * c_r + fast_sigmoid(gi) * fast_tanh(gG);
            float h2 = fast_sigmoid(go) * fast_tanh(c2);
            c_r = c2;
            out[(t * 128 + b) * 256 + j] = h2;
            float hn = __shfl_xor(h2, 1);
            float cn = __shfl_xor(c2, 1);
            if (!(j & 1)) {
                uint32 hp = pack_f16(h2, hn);
                vh_s[64 + (j >> 1)] = hp;
                hsh_s[j >> 1] = hp;
                hsh_s[128 + (j >> 1)] = pack_f16(c2, cn);
            }
        }
        __syncthreads();  // B6
    }
}

extern "C" void kernel_launch(void* const* d_in, const int* in_sizes, int n_in,
                              void* d_out, int out_size, void* d_ws, size_t ws_size,
                              hipStream_t stream) {
    const float* x    = (const float*)d_in[0];
    const float* We   = (const float*)d_in[1];
    const float* Ue   = (const float*)d_in[2];
    const float* v_e  = (const float*)d_in[3];
    const float* W_ih = (const float*)d_in[4];
    const float* W_hh = (const float*)d_in[5];
    const float* b_ih = (const float*)d_in[6];
    const float* b_hh = (const float*)d_in[7];
    float* out = (float*)d_out;

    char* w = (char*)d_ws;
    unsigned short* Uxg = (unsigned short*)w;   // 4 MB
    uint32* WrA = (uint32*)(w + 4194304);       // 256 KB
    uint32* WlB = (uint32*)(w + 4456448);       // 112 KB
    uint32* WsC = (uint32*)(w + 4571136);       // 400 KB
    uint32* WeT = (uint32*)(w + 4980736);       // 128 KB

    prep_weights<<<896, 256, 0, stream>>>(We, W_ih, W_hh, WrA, WlB, WsC, WeT);
    ux_kernel<<<256, 512, 0, stream>>>(x, Ue, Uxg);
    encoder_kernel<<<128, NT, 0, stream>>>(x, v_e, b_ih, b_hh, Uxg,
                                           (const uint4*)WrA, WlB,
                                           (const uint4*)WsC, (const uint4*)WeT, out);
}

// Round 8
// 4953.552 us; speedup vs baseline: 1.0138x; 1.0138x over previous
//
#include <hip/hip_runtime.h>
#include <hip/hip_bf16.h>
#include <hip/hip_fp16.h>

typedef unsigned int uint32;
typedef _Float16 hf2 __attribute__((ext_vector_type(2)));

#define NT 1024

// ---------- helpers ----------
__device__ __forceinline__ float bfu(unsigned short v) { return __uint_as_float(((uint32)v) << 16); }
__device__ __forceinline__ unsigned short f2bf(float f) {
    uint32 u = __float_as_uint(f);
    u = (u + 0x7fffu + ((u >> 16) & 1u)) >> 16;
    return (unsigned short)u;
}
__device__ __forceinline__ uint32 pack_f16(float a, float b) {
    __half ha = __float2half_rn(a), hb = __float2half_rn(b);
    return (uint32)__half_as_ushort(ha) | ((uint32)__half_as_ushort(hb) << 16);
}
__device__ __forceinline__ float fast_tanh(float x) {
    x = fminf(fmaxf(x, -15.f), 15.f);
    float e = __expf(2.f * x);
    return __fdividef(e - 1.f, e + 1.f);
}
__device__ __forceinline__ float fast_sigmoid(float x) {
    return __fdividef(1.f, 1.f + __expf(-x));
}
__device__ __forceinline__ float fdot2(uint32 w, uint32 v, float acc) {
#if __has_builtin(__builtin_amdgcn_fdot2)
    return __builtin_amdgcn_fdot2(__builtin_bit_cast(hf2, w), __builtin_bit_cast(hf2, v), acc, false);
#else
    __half2 wh = __builtin_bit_cast(__half2, w), vh = __builtin_bit_cast(__half2, v);
    float2 wf = __half22float2(wh), vf = __half22float2(vh);
    return fmaf(wf.y, vf.y, fmaf(wf.x, vf.x, acc));
#endif
}

// ---------- prep 1: f16 weight packs, 4 regions (uint4-interleaved) ----------
// Gate GEMV K-order: v = [xw(128) | h(256)], pair np covers elems (2np, 2np+1).
// A (regs)  WrA : (q*1024+gg)*4+p, q 0..15 -> np=4q+p -> W_ih cols (2np, 2np+1)
// B (LDS)   WlB : np*1024+gg,      np 0..27 -> h-pair np -> W_hh cols (2np, 2np+1)
// C (stream)WsC : (q*1024+gg)*4+p, q 0..24 -> h-pair hp=28+4q+p -> W_hh cols (2hp, 2hp+1)
// D (attn)  WeT : (q*1024+ch*128+s)*4+p, q 0..7 -> j0=ch*64+8q+2p -> We[s] cols (j0, j0+1)
__global__ void prep_weights(const float* __restrict__ We, const float* __restrict__ W_ih,
                             const float* __restrict__ W_hh, uint32* __restrict__ WrA,
                             uint32* __restrict__ WlB, uint32* __restrict__ WsC,
                             uint32* __restrict__ WeT) {
    int idx = blockIdx.x * 256 + threadIdx.x;
    if (idx < 65536) {
        int p = idx & 3, gg = (idx >> 2) & 1023, q = idx >> 12;
        int np = 4 * q + p;
        WrA[idx] = pack_f16(W_ih[gg * 128 + 2 * np], W_ih[gg * 128 + 2 * np + 1]);
    } else if (idx < 94208) {
        int i2 = idx - 65536;
        int gg = i2 & 1023, np = i2 >> 10;
        WlB[i2] = pack_f16(W_hh[gg * 256 + 2 * np], W_hh[gg * 256 + 2 * np + 1]);
    } else if (idx < 196608) {
        int i2 = idx - 94208;
        int p = i2 & 3, gg = (i2 >> 2) & 1023, q = i2 >> 12;
        int hp = 28 + 4 * q + p;
        WsC[i2] = pack_f16(W_hh[gg * 256 + 2 * hp], W_hh[gg * 256 + 2 * hp + 1]);
    } else if (idx < 229376) {
        int i2 = idx - 196608;
        int p = i2 & 3, s = (i2 >> 2) & 127, ch = (i2 >> 9) & 7, q = i2 >> 12;
        int j0 = ch * 64 + 8 * q + 2 * p;
        WeT[i2] = pack_f16(We[s * 512 + j0], We[s * 512 + j0 + 1]);
    }
}

// ---------- prep 2: Ux[b,s,n] = sum_t x[b,t,n] * Ue[s,t]  (bf16 out) ----------
__global__ void ux_kernel(const float* __restrict__ x, const float* __restrict__ Ue,
                          unsigned short* __restrict__ Uxg) {
    int b = blockIdx.x >> 1, h = blockIdx.x & 1;
    int n = threadIdx.x & 127, sg = threadIdx.x >> 7;
    int s0 = h * 64 + sg * 16;
    float acc[16];
#pragma unroll
    for (int k = 0; k < 16; ++k) acc[k] = 0.f;
    for (int t0 = 0; t0 < 128; t0 += 16) {
        float xv[16];
#pragma unroll
        for (int tt = 0; tt < 16; ++tt) xv[tt] = x[(b * 128 + t0 + tt) * 128 + n];
#pragma unroll
        for (int k = 0; k < 16; ++k) {
            const float4* uep = (const float4*)(Ue + (s0 + k) * 128 + t0);
            float4 u0 = uep[0], u1 = uep[1], u2 = uep[2], u3 = uep[3];
            acc[k] += xv[0] * u0.x + xv[1] * u0.y + xv[2] * u0.z + xv[3] * u0.w
                    + xv[4] * u1.x + xv[5] * u1.y + xv[6] * u1.z + xv[7] * u1.w
                    + xv[8] * u2.x + xv[9] * u2.y + xv[10] * u2.z + xv[11] * u2.w
                    + xv[12] * u3.x + xv[13] * u3.y + xv[14] * u3.z + xv[15] * u3.w;
        }
    }
#pragma unroll
    for (int k = 0; k < 16; ++k)
        Uxg[b * 16384 + (s0 + k) * 128 + n] = f2bf(acc[k]);
}

// ---------- main: 128 blocks x 1024 thr, one gate per thread. Residency:
// 64 xw-pairs in regs (amdgpu_waves_per_eu(4,4) -> 128-VGPR budget), 28 h-pairs
// in LDS, 100 h-pairs + We streamed (plain unrolled loads; compiler pipelines).
// All sync intra-block. ----------
__global__ __attribute__((amdgpu_waves_per_eu(4, 4))) __launch_bounds__(NT)
void encoder_kernel(const float* __restrict__ x, const float* __restrict__ v_e,
                    const float* __restrict__ b_ih, const float* __restrict__ b_hh,
                    const unsigned short* __restrict__ Uxg, const uint4* __restrict__ WrA4,
                    const uint32* __restrict__ WlB, const uint4* __restrict__ WsC4,
                    const uint4* __restrict__ WeT4, float* __restrict__ out) {
    __shared__ __align__(16) unsigned short Ux_s[16384];  // 32 KB [s][n] bf16
    __shared__ uint32 W_l[29696];   // 116 KB: gate g's 28 pairs at [g*29 .. g*29+27]
    __shared__ uint32 vh_s[192];    // v pairs: [xw(0..64) | h(64..192)]
    __shared__ uint32 hsh_s[256];   // hs pairs: [h(0..128) | c(128..256)]
    __shared__ float scr[1024];     // scratch: part1 / part2 / gates (disjoint lifetimes)
    __shared__ float web_s[128];
    __shared__ float ve_s[128];

    const int tid = threadIdx.x;
    const int b = blockIdx.x;
    const int lane7 = tid & 127;    // s (ph1) / n (ph2)
    const int ch = tid >> 7;        // 8-way chunk (wave-uniform)

    {   // stage Ux tile (coalesced)
        const uint4* src = (const uint4*)(Uxg + b * 16384);
        uint4* dst = (uint4*)Ux_s;
        dst[tid] = src[tid];
        dst[tid + 1024] = src[tid + 1024];
    }
    // stage LDS-resident gate weights: row g = tid, stride 29 (2-way max aliasing)
#pragma unroll
    for (int q = 0; q < 28; ++q) W_l[tid * 29 + q] = WlB[q * 1024 + tid];
    // reg-resident gate weights (all 64 xw pairs as 16 uint4)
    uint4 w_r4[16];
#pragma unroll
    for (int q = 0; q < 16; ++q) w_r4[q] = WrA4[q * 1024 + tid];
    const float bias_r = b_ih[tid] + b_hh[tid];
    float c_r = 0.f;  // c-state (threads 0..255)
    if (tid < 128) ve_s[tid] = v_e[tid];
    if (tid < 192) vh_s[tid] = 0u;
    if (tid < 256) hsh_s[tid] = 0u;
    __syncthreads();

    for (int t = 0; t < 128; ++t) {
        // x_t prefetch for softmax (wave 0)
        float2 xv = make_float2(0.f, 0.f);
        if (tid < 64) xv = *(const float2*)(x + (b * 128 + t) * 128 + 2 * tid);

        // ---- gate GEMV, h-part: LDS-resident 28 pairs ----
        float acc = bias_r;
#pragma unroll
        for (int q = 0; q < 28; ++q) acc = fdot2(W_l[tid * 29 + q], vh_s[64 + q], acc);

        // ---- gate GEMV, h-part: streamed 25 dwordx4 (compiler-scheduled) ----
#pragma unroll
        for (int q = 0; q < 25; ++q) {
            uint4 w = WsC4[q * 1024 + tid];
            acc = fdot2(w.x, vh_s[92 + 4 * q], acc);
            acc = fdot2(w.y, vh_s[93 + 4 * q], acc);
            acc = fdot2(w.z, vh_s[94 + 4 * q], acc);
            acc = fdot2(w.w, vh_s[95 + 4 * q], acc);
        }

        // ---- ph1: web[s] partials, thread (s=lane7, ch): j-pairs [32ch, 32ch+32) ----
        {
            float a1 = 0.f;
#pragma unroll
            for (int q = 0; q < 8; ++q) {
                uint4 w = WeT4[q * 1024 + tid];
                a1 = fdot2(w.x, hsh_s[ch * 32 + 4 * q + 0], a1);
                a1 = fdot2(w.y, hsh_s[ch * 32 + 4 * q + 1], a1);
                a1 = fdot2(w.z, hsh_s[ch * 32 + 4 * q + 2], a1);
                a1 = fdot2(w.w, hsh_s[ch * 32 + 4 * q + 3], a1);
            }
            scr[tid] = a1;  // [ch][s]
        }
        __syncthreads();  // B1
        if (tid < 128) {
            float w = 0.f;
#pragma unroll
            for (int g = 0; g < 8; ++g) w += scr[g * 128 + tid];
            web_s[tid] = w;
        }
        __syncthreads();  // B2

        // ---- ph2: score partials, thread (n=lane7, ch): s in [16ch, 16ch+16) ----
        {
            float a2 = 0.f;
#pragma unroll 4
            for (int k = 0; k < 16; ++k) {
                int ss = ch * 16 + k;
                a2 += ve_s[ss] * fast_tanh(web_s[ss] + bfu(Ux_s[ss * 128 + lane7]));
            }
            scr[tid] = a2;  // [ch][n]
        }
        __syncthreads();  // B3

        // ---- ph3: softmax + xw publish (wave 0; lane owns n=2l, 2l+1) ----
        if (tid < 64) {
            float v0 = 0.f, v1 = 0.f;
#pragma unroll
            for (int g = 0; g < 8; ++g) {
                v0 += scr[g * 128 + 2 * tid];
                v1 += scr[g * 128 + 2 * tid + 1];
            }
            float m = fmaxf(v0, v1);
#pragma unroll
            for (int off = 32; off > 0; off >>= 1) m = fmaxf(m, __shfl_xor(m, off));
            float e0 = __expf(v0 - m), e1 = __expf(v1 - m);
            float ssum = e0 + e1;
#pragma unroll
            for (int off = 32; off > 0; off >>= 1) ssum += __shfl_xor(ssum, off);
            float inv = __fdividef(1.f, ssum);
            vh_s[tid] = pack_f16(xv.x * e0 * inv, xv.y * e1 * inv);
        }
        __syncthreads();  // B4

        // ---- gate GEMV, xw-part from registers; write gates ----
#pragma unroll
        for (int q = 0; q < 16; ++q) {
            acc = fdot2(w_r4[q].x, vh_s[4 * q + 0], acc);
            acc = fdot2(w_r4[q].y, vh_s[4 * q + 1], acc);
            acc = fdot2(w_r4[q].z, vh_s[4 * q + 2], acc);
            acc = fdot2(w_r4[q].w, vh_s[4 * q + 3], acc);
        }
        scr[tid] = acc;   // gates, [gg]
        __syncthreads();  // B5

        // ---- pointwise + publish h/c (threads 0..255, thread = h-unit j) ----
        if (tid < 256) {
            const int j = tid;
            float gi = scr[j], gf = scr[256 + j], gG = scr[512 + j], go = scr[768 + j];
            float c2 = fast_sigmoid(gf) * c_r + fast_sigmoid(gi) * fast_tanh(gG);
            float h2 = fast_sigmoid(go) * fast_tanh(c2);
            c_r = c2;
            out[(t * 128 + b) * 256 + j] = h2;
            float hn = __shfl_xor(h2, 1);
            float cn = __shfl_xor(c2, 1);
            if (!(j & 1)) {
                uint32 hp = pack_f16(h2, hn);
                vh_s[64 + (j >> 1)] = hp;
                hsh_s[j >> 1] = hp;
                hsh_s[128 + (j >> 1)] = pack_f16(c2, cn);
            }
        }
        __syncthreads();  // B6
    }
}

extern "C" void kernel_launch(void* const* d_in, const int* in_sizes, int n_in,
                              void* d_out, int out_size, void* d_ws, size_t ws_size,
                              hipStream_t stream) {
    const float* x    = (const float*)d_in[0];
    const float* We   = (const float*)d_in[1];
    const float* Ue   = (const float*)d_in[2];
    const float* v_e  = (const float*)d_in[3];
    const float* W_ih = (const float*)d_in[4];
    const float* W_hh = (const float*)d_in[5];
    const float* b_ih = (const float*)d_in[6];
    const float* b_hh = (const float*)d_in[7];
    float* out = (float*)d_out;

    char* w = (char*)d_ws;
    unsigned short* Uxg = (unsigned short*)w;   // 4 MB
    uint32* WrA = (uint32*)(w + 4194304);       // 256 KB
    uint32* WlB = (uint32*)(w + 4456448);       // 112 KB
    uint32* WsC = (uint32*)(w + 4571136);       // 400 KB
    uint32* WeT = (uint32*)(w + 4980736);       // 128 KB

    prep_weights<<<896, 256, 0, stream>>>(We, W_ih, W_hh, WrA, WlB, WsC, WeT);
    ux_kernel<<<256, 512, 0, stream>>>(x, Ue, Uxg);
    encoder_kernel<<<128, NT, 0, stream>>>(x, v_e, b_ih, b_hh, Uxg,
                                           (const uint4*)WrA, WlB,
                                           (const uint4*)WsC, (const uint4*)WeT, out);
}

// Round 9
// 2809.328 us; speedup vs baseline: 1.7876x; 1.7633x over previous
//
#include <hip/hip_runtime.h>
#include <hip/hip_bf16.h>
#include <hip/hip_fp16.h>

typedef unsigned int uint32;
typedef _Float16 hf2 __attribute__((ext_vector_type(2)));
typedef uint32 u32x4 __attribute__((ext_vector_type(4)));

#define NT 1024

// ---------- helpers ----------
__device__ __forceinline__ float bfu(unsigned short v) { return __uint_as_float(((uint32)v) << 16); }
__device__ __forceinline__ unsigned short f2bf(float f) {
    uint32 u = __float_as_uint(f);
    u = (u + 0x7fffu + ((u >> 16) & 1u)) >> 16;
    return (unsigned short)u;
}
__device__ __forceinline__ uint32 pack_f16(float a, float b) {
    __half ha = __float2half_rn(a), hb = __float2half_rn(b);
    return (uint32)__half_as_ushort(ha) | ((uint32)__half_as_ushort(hb) << 16);
}
__device__ __forceinline__ float fast_tanh(float x) {
    x = fminf(fmaxf(x, -15.f), 15.f);
    float e = __expf(2.f * x);
    return __fdividef(e - 1.f, e + 1.f);
}
__device__ __forceinline__ float fast_sigmoid(float x) {
    return __fdividef(1.f, 1.f + __expf(-x));
}
// 2-way f16 dot with f32 accumulate (v_dot2_f32_f16), guarded fallback
__device__ __forceinline__ float fdot2(uint32 w, uint32 v, float acc) {
#if __has_builtin(__builtin_amdgcn_fdot2)
    return __builtin_amdgcn_fdot2(__builtin_bit_cast(hf2, w), __builtin_bit_cast(hf2, v), acc, false);
#else
    __half2 wh = __builtin_bit_cast(__half2, w), vh = __builtin_bit_cast(__half2, v);
    float2 wf = __half22float2(wh), vf = __half22float2(vh);
    return fmaf(wf.y, vf.y, fmaf(wf.x, vf.x, acc));
#endif
}
// nontemporal 16B load: bypass L1 allocation (nt bit), keep L2 residency
__device__ __forceinline__ uint4 ntload4(const uint4* p) {
    u32x4 v = __builtin_nontemporal_load((const u32x4*)p);
    uint4 r; r.x = v.x; r.y = v.y; r.z = v.z; r.w = v.w;
    return r;
}

// LDS flag ops (workgroup scope: ds ops only, no cache maintenance)
__device__ __forceinline__ void spin_ge(uint32* p, uint32 tgt) {
    int guard = 0;
    while (__hip_atomic_load(p, __ATOMIC_ACQUIRE, __HIP_MEMORY_SCOPE_WORKGROUP) < tgt) {
        __builtin_amdgcn_s_sleep(1);
        if (++guard > (1 << 22)) break;  // safety valve: wrong answer beats a hang
    }
}
__device__ __forceinline__ void st_flag(uint32* p, uint32 v) {
    __hip_atomic_store(p, v, __ATOMIC_RELEASE, __HIP_MEMORY_SCOPE_WORKGROUP);
}
__device__ __forceinline__ void add_flag(uint32* p, uint32 v) {
    __hip_atomic_fetch_add(p, v, __ATOMIC_RELEASE, __HIP_MEMORY_SCOPE_WORKGROUP);
}

// ---------- prep 1: f16-convert + re-layout weights ----------
// We2: uint4[64][128]; [jq][s] = 4 half2: (We[s][8jq+2p], We[s][8jq+2p+1]), p=0..3
//      (hs reduction dim j in [0,512) = [h(256)|c(256)])
// Wc2: uint4[192][256]; [np][q] = 4 half2: gate g=4q+p gets (W[g][2np], W[g][2np+1])
//      where K-dim n in [0,384) = [xw(128)|h(256)]:
//      W[g][n] = (n<128) ? W_ih[g][n] : W_hh[g][n-128]
__global__ void prep_weights(const float* __restrict__ We, const float* __restrict__ W_ih,
                             const float* __restrict__ W_hh, uint32* __restrict__ We2,
                             uint32* __restrict__ Wc2) {
    int idx = blockIdx.x * 256 + threadIdx.x;
    if (idx < 32768) {
        int p = idx & 3, s = (idx >> 2) & 127, jq = idx >> 9;
        int j = 8 * jq + 2 * p;
        We2[idx] = pack_f16(We[s * 512 + j], We[s * 512 + j + 1]);
    } else if (idx < 229376) {
        int i2 = idx - 32768;
        int p = i2 & 3, q = (i2 >> 2) & 255, np = i2 >> 10;
        int g = 4 * q + p;
        int n0 = 2 * np, n1 = 2 * np + 1;
        float w0, w1;
        if (n0 < 128) {
            w0 = W_ih[g * 128 + n0];
            w1 = W_ih[g * 128 + n1];
        } else {
            w0 = W_hh[g * 256 + (n0 - 128)];
            w1 = W_hh[g * 256 + (n1 - 128)];
        }
        Wc2[i2] = pack_f16(w0, w1);
    }
}

// ---------- prep 2: Ux[b,s,n] = sum_t x[b,t,n] * Ue[s,t]  (bf16 out) ----------
__global__ void ux_kernel(const float* __restrict__ x, const float* __restrict__ Ue,
                          unsigned short* __restrict__ Uxg) {
    int b = blockIdx.x >> 1, h = blockIdx.x & 1;
    int n = threadIdx.x & 127, sg = threadIdx.x >> 7;
    int s0 = h * 64 + sg * 16;
    float acc[16];
#pragma unroll
    for (int k = 0; k < 16; ++k) acc[k] = 0.f;
    for (int t0 = 0; t0 < 128; t0 += 16) {
        float xv[16];
#pragma unroll
        for (int tt = 0; tt < 16; ++tt) xv[tt] = x[(b * 128 + t0 + tt) * 128 + n];
#pragma unroll
        for (int k = 0; k < 16; ++k) {
            const float4* uep = (const float4*)(Ue + (s0 + k) * 128 + t0);
            float4 u0 = uep[0], u1 = uep[1], u2 = uep[2], u3 = uep[3];
            acc[k] += xv[0] * u0.x + xv[1] * u0.y + xv[2] * u0.z + xv[3] * u0.w
                    + xv[4] * u1.x + xv[5] * u1.y + xv[6] * u1.z + xv[7] * u1.w
                    + xv[8] * u2.x + xv[9] * u2.y + xv[10] * u2.z + xv[11] * u2.w
                    + xv[12] * u3.x + xv[13] * u3.y + xv[14] * u3.z + xv[15] * u3.w;
        }
    }
#pragma unroll
    for (int k = 0; k < 16; ++k)
        Uxg[b * 16384 + (s0 + k) * 128 + n] = f2bf(acc[k]);
}

// ---------- main: 128 blocks, wave-specialized, barrier-free step loop ----------
// Identical to the R4 kernel (best passing structure, 1659 us) except the
// weight-stream loads (Wc2q, We2q) are nontemporal: bypass L1 allocation to
// test whether the ~29 B/cyc/CU fill wall is L1-MSHR-limited.
__global__ __launch_bounds__(NT, 4)
void encoder_kernel(const float* __restrict__ x, const float* __restrict__ v_e,
                    const float* __restrict__ b_ih, const float* __restrict__ b_hh,
                    const unsigned short* __restrict__ Uxg, const uint4* __restrict__ We2q,
                    const uint4* __restrict__ Wc2q, float* __restrict__ out) {
    __shared__ __align__(16) unsigned short Ux_s[16384];  // 32 KB [s][n] bf16
    __shared__ __align__(16) float part4[6144];           // 24 KB [grp][1024 gates]
    __shared__ float part1[256];                          // [jg][s]
    __shared__ float part2[256];                          // [sg][n]
    __shared__ uint32 vh_s[192];    // half2 pairs of v=[xw(0..64)|h(64..192)]
    __shared__ uint32 hsh_s[256];   // half2 pairs of hs=[h(0..128)|c(128..256)]
    __shared__ float c_s[256];      // f32 c state
    __shared__ __align__(16) float bias_s[1024];
    __shared__ float ve_s[128];
    __shared__ uint32 h_flag, xw_flag, cnt1, cnt2, cnt4, cnt5;
    __shared__ float pad_force[4096];  // LDS pad -> 1 block/CU

    const int tid = threadIdx.x;
    const int b = blockIdx.x;

    {   // load this batch's Ux tile (coalesced)
        const uint4* src = (const uint4*)(Uxg + b * 16384);
        uint4* dst = (uint4*)Ux_s;
        for (int i = tid; i < 2048; i += NT) dst[i] = src[i];
    }
    bias_s[tid] = b_ih[tid] + b_hh[tid];
    if (tid < 128) ve_s[tid] = v_e[tid];
    if (tid < 192) vh_s[tid] = 0u;
    if (tid < 256) { hsh_s[tid] = 0u; c_s[tid] = 0.f; }
    if (tid == 0) { h_flag = 0; xw_flag = 0; cnt1 = 0; cnt2 = 0; cnt4 = 0; cnt5 = 0; }
    __syncthreads();  // the only barrier; all threads reach it

    if (tid < 768) {
        // ================= A-group =================
        const int ol = tid & 127, g = tid >> 7;
        const uint4* wc = Wc2q + 2 * ol;
        for (int t = 0; t < 128; ++t) {
            float a0 = 0.f, a1 = 0.f, a2 = 0.f, a3 = 0.f;
            float a4 = 0.f, a5 = 0.f, a6 = 0.f, a7 = 0.f;
            spin_ge(&h_flag, (uint32)t);
            if (g < 4) {
                // h-part: np in [64+32g, 64+32g+32)
                const int np0 = 64 + g * 32;
#pragma unroll 8
                for (int i = 0; i < 32; ++i) {
                    int np = np0 + i;
                    uint32 vp = vh_s[np];
                    uint4 w0 = ntload4(wc + np * 256);
                    uint4 w1 = ntload4(wc + np * 256 + 1);
                    a0 = fdot2(w0.x, vp, a0); a1 = fdot2(w0.y, vp, a1);
                    a2 = fdot2(w0.z, vp, a2); a3 = fdot2(w0.w, vp, a3);
                    a4 = fdot2(w1.x, vp, a4); a5 = fdot2(w1.y, vp, a5);
                    a6 = fdot2(w1.z, vp, a6); a7 = fdot2(w1.w, vp, a7);
                }
            } else {
                // ph1: web partial over hs-chunk jg
                const int s = ol, jg = g - 4;
                float acc = 0.f;
#pragma unroll 8
                for (int jq = jg * 32; jq < jg * 32 + 32; ++jq) {
                    uint4 w = ntload4(We2q + jq * 128 + s);
                    acc = fdot2(w.x, hsh_s[4 * jq + 0], acc);
                    acc = fdot2(w.y, hsh_s[4 * jq + 1], acc);
                    acc = fdot2(w.z, hsh_s[4 * jq + 2], acc);
                    acc = fdot2(w.w, hsh_s[4 * jq + 3], acc);
                }
                part1[jg * 128 + s] = acc;
                if ((tid & 63) == 0) add_flag(&cnt1, 1);
                // xw-part: np in [32(g-4), 32(g-4)+32)
                spin_ge(&xw_flag, (uint32)(t + 1));
                const int np0 = jg * 32;
#pragma unroll 8
                for (int i = 0; i < 32; ++i) {
                    int np = np0 + i;
                    uint32 vp = vh_s[np];
                    uint4 w0 = ntload4(wc + np * 256);
                    uint4 w1 = ntload4(wc + np * 256 + 1);
                    a0 = fdot2(w0.x, vp, a0); a1 = fdot2(w0.y, vp, a1);
                    a2 = fdot2(w0.z, vp, a2); a3 = fdot2(w0.w, vp, a3);
                    a4 = fdot2(w1.x, vp, a4); a5 = fdot2(w1.y, vp, a5);
                    a6 = fdot2(w1.z, vp, a6); a7 = fdot2(w1.w, vp, a7);
                }
            }
            float4* p4 = (float4*)&part4[g * 1024 + 8 * ol];
            p4[0] = make_float4(a0, a1, a2, a3);
            p4[1] = make_float4(a4, a5, a6, a7);
            if ((tid & 63) == 0) add_flag(&cnt4, 1);
        }
    } else {
        // ================= B-group =================
        const int bt = tid - 768, l = tid & 63;
        const int n = bt & 127, sg = bt >> 7;
        for (int t = 0; t < 128; ++t) {
            float2 xt2;
            if (bt < 64) xt2 = *(const float2*)(x + (b * 128 + t) * 128 + 2 * l);
            spin_ge(&cnt1, (uint32)(4 * (t + 1)));
            // per-wave redundant web (no extra sync): lane l holds web[l], web[64+l]
            float web_lo = part1[l] + part1[128 + l];
            float web_hi = part1[64 + l] + part1[192 + l];
            float wsel = sg ? web_hi : web_lo;
            // ph2: scores partial over s-chunk sg
            float acc = 0.f;
#pragma unroll 8
            for (int k = 0; k < 64; ++k) {
                float wv = __shfl(wsel, k);
                float a = wv + bfu(Ux_s[(sg * 64 + k) * 128 + n]);
                acc += ve_s[sg * 64 + k] * fast_tanh(a);
            }
            part2[sg * 128 + n] = acc;
            if (l == 0) add_flag(&cnt2, 1);
            if (bt < 64) {
                // ph3: softmax + xw (wave 12 only); lane l owns n=2l, 2l+1
                spin_ge(&cnt2, (uint32)(4 * (t + 1)));
                float v0 = part2[2 * l] + part2[128 + 2 * l];
                float v1 = part2[2 * l + 1] + part2[129 + 2 * l];
                float m = fmaxf(v0, v1);
#pragma unroll
                for (int off = 32; off > 0; off >>= 1) m = fmaxf(m, __shfl_xor(m, off));
                float e0 = __expf(v0 - m), e1 = __expf(v1 - m);
                float ssum = e0 + e1;
#pragma unroll
                for (int off = 32; off > 0; off >>= 1) ssum += __shfl_xor(ssum, off);
                float inv = __fdividef(1.f, ssum);
                vh_s[l] = pack_f16(xt2.x * e0 * inv, xt2.y * e1 * inv);
                if (bt == 0) st_flag(&xw_flag, (uint32)(t + 1));
            }
            // ph5: gate reduce + LSTM pointwise (all 4 B-waves; thread = h-unit j)
            spin_ge(&cnt4, (uint32)(12 * (t + 1)));
            const int j = bt;
            float gi = bias_s[j], gf = bias_s[256 + j];
            float gg = bias_s[512 + j], go = bias_s[768 + j];
#pragma unroll
            for (int gr = 0; gr < 6; ++gr) {
                const float* pp = part4 + gr * 1024;
                gi += pp[j]; gf += pp[256 + j];
                gg += pp[512 + j]; go += pp[768 + j];
            }
            float c = c_s[j];
            float c2 = fast_sigmoid(gf) * c + fast_sigmoid(gi) * fast_tanh(gg);
            float h2v = fast_sigmoid(go) * fast_tanh(c2);
            c_s[j] = c2;
            out[(t * 128 + b) * 256 + j] = h2v;
            float hn = __shfl_xor(h2v, 1);
            float cn = __shfl_xor(c2, 1);
            if (!(j & 1)) {
                uint32 hp = pack_f16(h2v, hn);
                vh_s[64 + (j >> 1)] = hp;       // v h-pairs for gate GEMV
                hsh_s[j >> 1] = hp;             // hs h-pairs for ph1
                hsh_s[128 + (j >> 1)] = pack_f16(c2, cn);  // hs c-pairs
            }
            if (l == 0) add_flag(&cnt5, 1);
            if (bt == 0) {
                spin_ge(&cnt5, (uint32)(4 * (t + 1)));
                st_flag(&h_flag, (uint32)(t + 1));
            }
        }
        // keep pad_force alive (never true at runtime)
        if (__hip_atomic_load(&h_flag, __ATOMIC_RELAXED, __HIP_MEMORY_SCOPE_WORKGROUP) == 0xffffffffu)
            pad_force[tid & 4095] = 0.f;
    }
}

extern "C" void kernel_launch(void* const* d_in, const int* in_sizes, int n_in,
                              void* d_out, int out_size, void* d_ws, size_t ws_size,
                              hipStream_t stream) {
    const float* x    = (const float*)d_in[0];
    const float* We   = (const float*)d_in[1];
    const float* Ue   = (const float*)d_in[2];
    const float* v_e  = (const float*)d_in[3];
    const float* W_ih = (const float*)d_in[4];
    const float* W_hh = (const float*)d_in[5];
    const float* b_ih = (const float*)d_in[6];
    const float* b_hh = (const float*)d_in[7];
    float* out = (float*)d_out;

    char* w = (char*)d_ws;
    unsigned short* Uxg = (unsigned short*)w;      // 4 MB
    uint32* We2 = (uint32*)(w + 4194304);          // 128 KB
    uint32* Wc2 = (uint32*)(w + 4325376);          // 768 KB

    prep_weights<<<896, 256, 0, stream>>>(We, W_ih, W_hh, We2, Wc2);
    ux_kernel<<<256, 512, 0, stream>>>(x, Ue, Uxg);
    encoder_kernel<<<128, NT, 0, stream>>>(x, v_e, b_ih, b_hh, Uxg,
                                           (const uint4*)We2, (const uint4*)Wc2, out);
}